// Round 1
// 309.331 us; speedup vs baseline: 1.6002x; 1.6002x over previous
//
#include <hip/hip_runtime.h>

// EdgeAttention fused kernel for MI355X (gfx950).
// One workgroup (1024 thr = 16 waves) per (b,l): projects K/V2 into LDS (bf16,
// swizzled), then each wave owns one 16-row i-tile: Q proj -> S = Q K^T ->
// softmax(j) -> (P V2) * V1 -> Wo proj.
// Register-lean flow: Qf freed before S loop (Q pre-converted to bf16 frags),
// S freed before PV2 loop (P pre-converted), V1 projected after attention from
// retained aE frags, softmax denominator folded into the V1 multiply.
// MFMA layouts (m89/m91/m120-verified):
//   A-frag: a[j] = A[m = lane&15][k = (lane>>4)*8 + j]
//   B-frag: b[j] = B^T[n = lane&15][k = (lane>>4)*8 + j]   (dot-of-rows)
//   C/D   : c[r] = D[m = (lane>>4)*4 + r][n = lane&15]

typedef __bf16 bf16x8 __attribute__((ext_vector_type(8)));
typedef float  f32x4  __attribute__((ext_vector_type(4)));

#define MFMA(a, b, c) __builtin_amdgcn_mfma_f32_16x16x32_bf16((a), (b), (c), 0, 0, 0)

__device__ __forceinline__ unsigned short rne_bf16(float f) {
  unsigned int u = __float_as_uint(f);
  u += 0x7fffu + ((u >> 16) & 1u);   // round-to-nearest-even
  return (unsigned short)(u >> 16);
}

// load 8 consecutive fp32 (16B aligned) and convert to a bf16x8 A-fragment
__device__ __forceinline__ bf16x8 cvt_frag(const float* __restrict__ p) {
  f32x4 a = *(const f32x4*)p;
  f32x4 b = *(const f32x4*)(p + 4);
  union { bf16x8 v; unsigned short u[8]; } t;
  t.u[0] = rne_bf16(a[0]); t.u[1] = rne_bf16(a[1]);
  t.u[2] = rne_bf16(a[2]); t.u[3] = rne_bf16(a[3]);
  t.u[4] = rne_bf16(b[0]); t.u[5] = rne_bf16(b[1]);
  t.u[6] = rne_bf16(b[2]); t.u[7] = rne_bf16(b[3]);
  return t.v;
}

// Setup: convert the 5 weight matrices fp32 -> bf16 into d_ws.
__global__ void cvt_weights(const float* __restrict__ Wq, const float* __restrict__ Wk,
                            const float* __restrict__ Wv1, const float* __restrict__ Wv2,
                            const float* __restrict__ Wo, unsigned short* __restrict__ ws) {
  int t = blockIdx.x * 256 + threadIdx.x;   // 0..16383
  ws[t]             = rne_bf16(Wq[t]);
  ws[16384 + t]     = rne_bf16(Wk[t]);
  ws[2 * 16384 + t] = rne_bf16(Wv1[t]);
  ws[3 * 16384 + t] = rne_bf16(Wv2[t]);
  ws[4 * 16384 + t] = rne_bf16(Wo[t]);
}

__global__ __launch_bounds__(1024, 4)
void edge_attn_kernel(const float* __restrict__ ef,
                      const unsigned short* __restrict__ wbf,
                      const float* __restrict__ bq, const float* __restrict__ bk,
                      const float* __restrict__ bv1, const float* __restrict__ bv2,
                      const float* __restrict__ bo,
                      float* __restrict__ out) {
  // K rows (j-major) swizzled: elem (j,o) at j*128 + (((o>>3) ^ (j&15))<<3) + (o&7)
  __shared__ unsigned short Kb[256 * 128];
  // V2 transposed (d-major) swizzled: elem (j,d) at d*256 + (((j>>3) ^ (d&15))<<3) + (j&7)
  __shared__ unsigned short V2t[128 * 256];
  // per-wave fragment-linear scratch for C->A layout round-trips (16x32 bf16)
  __shared__ unsigned short chunk[16][512];

  const int tid  = threadIdx.x;
  const int lane = tid & 63;
  const int wv   = tid >> 6;    // wave 0..15
  const int lc   = lane & 15;
  const int q4   = lane >> 4;
  const int bb   = blockIdx.x >> 8;
  const int lb   = blockIdx.x & 255;

  const unsigned short* WqB  = wbf;
  const unsigned short* WkB  = wbf + 16384;
  const unsigned short* Wv1B = wbf + 2 * 16384;
  const unsigned short* Wv2B = wbf + 3 * 16384;
  const unsigned short* WoB  = wbf + 4 * 16384;

  const f32x4 Z4 = {0.f, 0.f, 0.f, 0.f};

  // ---------------- Phase 1: K = F@Wk^T + bk, V2 = F@Wv2^T + bv2 into LDS ---
  // wave wv produces j rows [wv*16, wv*16+16)
  {
    const float* Frow = ef + ((size_t)(bb * 256 + lb)) * (256 * 128);
    const int j0 = wv * 16;
    bf16x8 aF[4];
    const float* rp = Frow + (j0 + lc) * 128 + q4 * 8;
    #pragma unroll
    for (int kc = 0; kc < 4; ++kc) aF[kc] = cvt_frag(rp + kc * 32);

    f32x4 accK[8], accV[8];
    #pragma unroll
    for (int n = 0; n < 8; ++n) { accK[n] = Z4; accV[n] = Z4; }
    #pragma unroll
    for (int kc = 0; kc < 4; ++kc) {
      #pragma unroll
      for (int n = 0; n < 8; ++n) {
        bf16x8 bwk = *(const bf16x8*)(WkB  + (n * 16 + lc) * 128 + kc * 32 + q4 * 8);
        bf16x8 bwv = *(const bf16x8*)(Wv2B + (n * 16 + lc) * 128 + kc * 32 + q4 * 8);
        accK[n] = MFMA(aF[kc], bwk, accK[n]);
        accV[n] = MFMA(aF[kc], bwv, accV[n]);
      }
    }
    #pragma unroll
    for (int n = 0; n < 8; ++n) {
      const int o = n * 16 + lc;            // output channel (d index for V2)
      const float bkv = bk[o];
      const float bvv = bv2[o];
      #pragma unroll
      for (int r = 0; r < 4; ++r) {
        const int j = j0 + q4 * 4 + r;
        Kb[j * 128 + (((o >> 3) ^ (j & 15)) << 3) + (o & 7)] = rne_bf16(accK[n][r] + bkv);
        V2t[o * 256 + (((j >> 3) ^ lc) << 3) + (j & 7)]      = rne_bf16(accV[n][r] + bvv);
      }
    }
  }
  __syncthreads();

  // ---------------- Phase 2: per-wave i-tile attention ----------------------
  const float scale = 0.08838834764831845f;  // 1/sqrt(128)
  unsigned short* chw = chunk[wv];
  const int i0 = wv * 16;

  // E-row A-fragments (used by Q projection now, V1 projection later)
  bf16x8 aE[4];
  {
    const float* rp = ef + (((size_t)(bb * 256 + i0 + lc)) * 256 + lb) * 128 + q4 * 8;
    #pragma unroll
    for (int kc = 0; kc < 4; ++kc) aE[kc] = cvt_frag(rp + kc * 32);
  }

  // Q projection (C-layout register frags)
  f32x4 Qf[8];
  #pragma unroll
  for (int n = 0; n < 8; ++n) Qf[n] = Z4;
  #pragma unroll
  for (int kc = 0; kc < 4; ++kc) {
    #pragma unroll
    for (int n = 0; n < 8; ++n) {
      bf16x8 bwq = *(const bf16x8*)(WqB + (n * 16 + lc) * 128 + kc * 32 + q4 * 8);
      Qf[n] = MFMA(aE[kc], bwq, Qf[n]);
    }
  }

  // (Q + bq) * scale -> bf16 A-frags; frees Qf before the S loop
  bf16x8 aQ[4];
  #pragma unroll
  for (int kc = 0; kc < 4; ++kc) {
    #pragma unroll
    for (int h = 0; h < 2; ++h) {
      const int nt = kc * 2 + h;
      const float bqv = bq[nt * 16 + lc];
      #pragma unroll
      for (int r = 0; r < 4; ++r) {
        const int k = h * 16 + lc;
        const int m = q4 * 4 + r;
        chw[((m + ((k >> 3) << 4)) << 3) + (k & 7)] = rne_bf16((Qf[nt][r] + bqv) * scale);
      }
    }
    aQ[kc] = *(const bf16x8*)(chw + lane * 8);
  }

  // S = (Q*scale) @ K^T : 16 j-tiles of C-frags
  f32x4 S[16];
  #pragma unroll
  for (int jt = 0; jt < 16; ++jt) S[jt] = Z4;
  #pragma unroll
  for (int kc = 0; kc < 4; ++kc) {
    #pragma unroll
    for (int jt = 0; jt < 16; ++jt) {
      const int j = jt * 16 + lc;
      bf16x8 bK = *(const bf16x8*)(Kb + j * 128 + (((kc * 4 + q4) ^ lc) << 3));
      S[jt] = MFMA(aQ[kc], bK, S[jt]);
    }
  }

  // softmax over j (row = i0 + q4*4 + r lives in the 16-lane group);
  // denominator deferred to the epilogue (inv[r])
  float inv[4];
  #pragma unroll
  for (int r = 0; r < 4; ++r) {
    float mx = -1e30f;
    #pragma unroll
    for (int jt = 0; jt < 16; ++jt) mx = fmaxf(mx, S[jt][r]);
    mx = fmaxf(mx, __shfl_xor(mx, 1));
    mx = fmaxf(mx, __shfl_xor(mx, 2));
    mx = fmaxf(mx, __shfl_xor(mx, 4));
    mx = fmaxf(mx, __shfl_xor(mx, 8));
    float sm = 0.f;
    #pragma unroll
    for (int jt = 0; jt < 16; ++jt) {
      float e = __expf(S[jt][r] - mx);
      S[jt][r] = e;
      sm += e;
    }
    sm += __shfl_xor(sm, 1);
    sm += __shfl_xor(sm, 2);
    sm += __shfl_xor(sm, 4);
    sm += __shfl_xor(sm, 8);
    inv[r] = 1.0f / sm;
  }

  // P (unnormalized) -> bf16 A-frags; frees S before the PV2 loop
  bf16x8 aP[8];
  #pragma unroll
  for (int kc = 0; kc < 8; ++kc) {
    #pragma unroll
    for (int h = 0; h < 2; ++h) {
      const int jt = kc * 2 + h;
      #pragma unroll
      for (int r = 0; r < 4; ++r) {
        const int k = h * 16 + lc;
        const int m = q4 * 4 + r;
        chw[((m + ((k >> 3) << 4)) << 3) + (k & 7)] = rne_bf16(S[jt][r]);
      }
    }
    aP[kc] = *(const bf16x8*)(chw + lane * 8);
  }

  // ctx_raw = P @ V2   (C-layout)
  f32x4 Cx[8];
  #pragma unroll
  for (int n = 0; n < 8; ++n) Cx[n] = Z4;
  #pragma unroll
  for (int kc = 0; kc < 8; ++kc) {
    #pragma unroll
    for (int n = 0; n < 8; ++n) {
      const int d = n * 16 + lc;
      bf16x8 bV = *(const bf16x8*)(V2t + d * 256 + (((kc * 4 + q4) ^ lc) << 3));
      Cx[n] = MFMA(aP[kc], bV, Cx[n]);
    }
  }

  // V1 projection (from retained aE), then Cx = Cx * inv[r] * (V1 + bv1)
  f32x4 V1f[8];
  #pragma unroll
  for (int n = 0; n < 8; ++n) V1f[n] = Z4;
  #pragma unroll
  for (int kc = 0; kc < 4; ++kc) {
    #pragma unroll
    for (int n = 0; n < 8; ++n) {
      bf16x8 bwv = *(const bf16x8*)(Wv1B + (n * 16 + lc) * 128 + kc * 32 + q4 * 8);
      V1f[n] = MFMA(aE[kc], bwv, V1f[n]);
    }
  }
  #pragma unroll
  for (int n = 0; n < 8; ++n) {
    const float bvv = bv1[n * 16 + lc];
    #pragma unroll
    for (int r = 0; r < 4; ++r) Cx[n][r] *= inv[r] * (V1f[n][r] + bvv);
  }

  // out = ctx @ Wo^T + bo : convert Cx -> A-frags first (frees Cx)
  bf16x8 aC[4];
  #pragma unroll
  for (int kc = 0; kc < 4; ++kc) {
    #pragma unroll
    for (int h = 0; h < 2; ++h) {
      const int nt = kc * 2 + h;
      #pragma unroll
      for (int r = 0; r < 4; ++r) {
        const int k = h * 16 + lc;
        const int m = q4 * 4 + r;
        chw[((m + ((k >> 3) << 4)) << 3) + (k & 7)] = rne_bf16(Cx[nt][r]);
      }
    }
    aC[kc] = *(const bf16x8*)(chw + lane * 8);
  }
  f32x4 O[8];
  #pragma unroll
  for (int n = 0; n < 8; ++n) O[n] = Z4;
  #pragma unroll
  for (int kc = 0; kc < 4; ++kc) {
    #pragma unroll
    for (int n = 0; n < 8; ++n) {
      bf16x8 bw = *(const bf16x8*)(WoB + (n * 16 + lc) * 128 + kc * 32 + q4 * 8);
      O[n] = MFMA(aC[kc], bw, O[n]);
    }
  }
  #pragma unroll
  for (int n = 0; n < 8; ++n) {
    const float bov = bo[n * 16 + lc];
    #pragma unroll
    for (int r = 0; r < 4; ++r) {
      const int i = i0 + q4 * 4 + r;
      out[(((size_t)(bb * 256 + i)) * 256 + lb) * 128 + n * 16 + lc] = O[n][r] + bov;
    }
  }
}

extern "C" void kernel_launch(void* const* d_in, const int* in_sizes, int n_in,
                              void* d_out, int out_size, void* d_ws, size_t ws_size,
                              hipStream_t stream) {
  const float* ef   = (const float*)d_in[0];
  const float* Wq   = (const float*)d_in[1];
  const float* bqp  = (const float*)d_in[2];
  const float* Wk   = (const float*)d_in[3];
  const float* bkp  = (const float*)d_in[4];
  const float* Wv1  = (const float*)d_in[5];
  const float* bv1p = (const float*)d_in[6];
  const float* Wv2  = (const float*)d_in[7];
  const float* bv2p = (const float*)d_in[8];
  const float* Wo   = (const float*)d_in[9];
  const float* bop  = (const float*)d_in[10];
  unsigned short* wbf = (unsigned short*)d_ws;   // 5 * 128*128 bf16 = 160 KB

  cvt_weights<<<64, 256, 0, stream>>>(Wq, Wk, Wv1, Wv2, Wo, wbf);
  edge_attn_kernel<<<512, 1024, 0, stream>>>(ef, wbf, bqp, bkp, bv1p, bv2p, bop,
                                             (float*)d_out);
}